// Round 6
// baseline (1917.472 us; speedup 1.0000x reference)
//
#include <hip/hip_runtime.h>

#define NN 50000
#define EE 800000
#define GG 512
#define TILES 782          // ceil(NN/64)
#define NBLK 768           // 3 blocks/CU needed; capacity 4-5/CU -> co-resident
#define NTHR 256
#define NTOT (NBLK * NTHR) // 196608 threads
#define NWAVE (NTOT / 64)  // 3072 waves

typedef __attribute__((ext_vector_type(8))) short short8;
typedef __attribute__((ext_vector_type(4))) float f32x4;

// ---- bf16 helpers ----
__device__ __forceinline__ float b2f(unsigned short u) {
    union { unsigned int i; float f; } c;
    c.i = ((unsigned int)u) << 16;
    return c.f;
}
__device__ __forceinline__ unsigned short f2b(float f) {
    union { float f; unsigned int i; } c;
    c.f = f;
    const unsigned int r = c.i + 0x7FFFu + ((c.i >> 16) & 1u);  // rne
    return (unsigned short)(r >> 16);
}
__device__ __forceinline__ int rfl(int v) { return __builtin_amdgcn_readfirstlane(v); }

struct Params {
    const float* x; const int* ei; const int* batch;
    const float* w1a; const float* b1a; const float* w1b; const float* b1b; const float* g1; const float* be1;
    const float* w2a; const float* b2a; const float* w2b; const float* b2b; const float* g2; const float* be2;
    const float* w3a; const float* b3a; const float* w3b; const float* b3b; const float* g3; const float* be3;
    const float* wlin0; const float* blin0; const float* wfc1; const float* bfc1;
    float* out; void* ws;
};

// Zero the barrier + global counters each replay (workspace is re-poisoned
// between harness iterations). 1 block, launched before the mega kernel.
__global__ void init_kernel(int* bar) {
    if (threadIdx.x < 32) bar[threadIdx.x] = 0;
}

// ===========================================================================
// Persistent mega-kernel with a software grid barrier (REGULAR launch — no
// hipLaunchCooperativeKernel: coop launches break the harness's hipGraph
// capture; rounds 4/5 evidence). Monotonic arrive counter, device-scope
// atomics, bounded spin (residency failure -> wrong answer, not a hang).
// ===========================================================================
__global__ __launch_bounds__(256, 4) void mega_kernel(Params p) {
    // ---- workspace layout ----
    int* ibase   = (int*)p.ws;
    int* counts  = ibase;            // 50000 (= deg[])
    int* rowbeg  = ibase + 50000;    // 50000
    int* cursor  = ibase + 100000;   // 50000
    int* gctr    = ibase + 150000;   // 16 ints (zeroed by init_kernel)
    int* bar     = ibase + 150016;   // 16 ints (zeroed by init_kernel)
    int* col     = ibase + 150032;   // 800000 -> end 950032, pad to 950048
    float* fbase = (float*)p.ws + 950048;
    float* stats = fbase;            // 3 x 1024
    float* xpool = stats + 3072;     // 32768
    unsigned short* zbf   = (unsigned short*)(fbase + 35840);  // NN*64
    unsigned short* xbf   = zbf + 3200000;
    unsigned short* t0    = xbf + 3200000;
    unsigned short* t1    = t0 + 3200000;
    unsigned short* wfrag = t1 + 3200000;   // 6 x 4096 bf16

    __shared__ __align__(16) unsigned char smraw[27648];

    const int gtid = blockIdx.x * NTHR + threadIdx.x;
    const int lane = threadIdx.x & 63;

    int bphase = 0;
#define GSYNC() do {                                                           \
        __syncthreads();                                                       \
        ++bphase;                                                              \
        if (threadIdx.x == 0) {                                                \
            __threadfence();                                                   \
            __hip_atomic_fetch_add(bar, 1, __ATOMIC_RELEASE,                   \
                                   __HIP_MEMORY_SCOPE_AGENT);                  \
            int spins = 0;                                                     \
            while (__hip_atomic_load(bar, __ATOMIC_ACQUIRE,                    \
                                     __HIP_MEMORY_SCOPE_AGENT)                 \
                   < bphase * NBLK) {                                          \
                __builtin_amdgcn_s_sleep(2);                                   \
                if (++spins > (1 << 17)) break;                                \
            }                                                                  \
            __threadfence();                                                   \
        }                                                                      \
        __syncthreads();                                                       \
    } while (0)

    // ================= P0: prep =================
    for (int i = gtid; i < 800000; i += NTOT) {
        const float4 v = ((const float4*)p.x)[i];
        ushort4 o;
        o.x = f2b(v.x); o.y = f2b(v.y); o.z = f2b(v.z); o.w = f2b(v.w);
        ((ushort4*)xbf)[i] = o;
    }
    for (int i = gtid; i < 12500; i += NTOT) ((int4*)counts)[i] = make_int4(0, 0, 0, 0);
    for (int i = gtid; i < 8960; i += NTOT) ((float4*)stats)[i] = make_float4(0.f, 0.f, 0.f, 0.f);
    if (blockIdx.x >= NBLK - 6) {   // weight swizzle: fp32 [k][n] -> B-frag order
        const int wi = blockIdx.x - (NBLK - 6);
        const float* w = (wi == 0) ? p.w1a : (wi == 1) ? p.w1b : (wi == 2) ? p.w2a
                       : (wi == 3) ? p.w2b : (wi == 4) ? p.w3a : p.w3b;
        unsigned short* o = wfrag + wi * 4096;
        #pragma unroll
        for (int it = 0; it < 2; ++it) {
            const int idx = it * 256 + threadIdx.x;
            const int fid = idx >> 6, ln = idx & 63;
            const int kt = fid >> 2, nt = fid & 3;
            const int kbase = kt * 32 + (ln >> 4) * 8;
            const int n = nt * 16 + (ln & 15);
            #pragma unroll
            for (int j = 0; j < 8; ++j)
                o[idx * 8 + j] = f2b(w[(kbase + j) * 64 + n]);
        }
    }
    GSYNC();

    // ================= P1: histogram =================
    for (int e = gtid; e < EE; e += NTOT) atomicAdd(&counts[p.ei[EE + e]], 1);
    GSYNC();

    // ================= P2: alloc (order-free rowbeg via wave-agg atomics) ====
    {
        const int gw = gtid >> 6;
        if (gw < TILES) {
            const int r = gw * 64 + lane;
            const int cnt = (r < NN) ? counts[r] : 0;
            int incl = cnt;
            #pragma unroll
            for (int off = 1; off < 64; off <<= 1) {
                const int tv = __shfl_up(incl, off);
                if (lane >= off) incl += tv;
            }
            const int tot = __shfl(incl, 63);
            int base = 0;
            if (lane == 63) base = atomicAdd(gctr, tot);
            base = __shfl(base, 63);
            if (r < NN) {
                const int b0 = base + incl - cnt;
                rowbeg[r] = b0;
                cursor[r] = b0;
            }
        }
    }
    GSYNC();

    // ================= P3: fill (8 classes x 96 chunk-blocks) =================
    {
        const int cls = blockIdx.x & 7;
        const int idx = blockIdx.x >> 3;            // 0..95
        for (int e = idx * NTHR + threadIdx.x; e < EE; e += 96 * NTHR) {
            const int dst = p.ei[EE + e];
            if (dst / 6250 == cls) {
                const int pos = atomicAdd(&cursor[dst], 1);
                col[pos] = p.ei[e];
            }
        }
    }
    GSYNC();

    // ================= 3 GIN layers =================
    unsigned short* wlds = (unsigned short*)smraw;                                 // 8192 ush
    unsigned short (*ldsT)[16][72] = (unsigned short (*)[16][72])(smraw + 16384);  // 4x16x72
    float* red = (float*)(smraw + 16384 + 9216);                                   // 512 f

    for (int l = 0; l < 3; ++l) {
        const float* ba = (l == 0) ? p.b1a : (l == 1) ? p.b2a : p.b3a;
        const float* bb = (l == 0) ? p.b1b : (l == 1) ? p.b2b : p.b3b;
        const float* gp = (l == 1) ? p.g1 : p.g2;
        const float* bp = (l == 1) ? p.be1 : p.be2;
        const unsigned short* hin = (l == 0) ? xbf : (l == 1) ? t0 : t1;
        unsigned short* tout = (l == 1) ? t1 : t0;
        const unsigned short* wfa = wfrag + (l * 2 + 0) * 4096;
        const unsigned short* wfb = wfrag + (l * 2 + 1) * 4096;
        float* statsL = stats + l * 1024;
        const float* statsP = stats + (l ? (l - 1) : 0) * 1024;

        // ---- gather: 3072 waves, 17 strided rows each ----
        {
            float scl = 1.0f, sft = 0.0f;
            if (l > 0) {   // folded BN finalize of previous layer
                float s = 0.f, sq = 0.f;
                #pragma unroll
                for (int k = 0; k < 8; ++k) {
                    s += statsP[k * 128 + lane];
                    sq += statsP[k * 128 + 64 + lane];
                }
                const float mean = s * (1.0f / NN);
                const float var = sq * (1.0f / NN) - mean * mean;
                scl = gp[lane] * rsqrtf(var + 1e-5f);
                sft = bp[lane] - mean * scl;
            }
            const int gw = gtid >> 6;
            for (int ii = 0; ii < 17; ++ii) {
                const int row = gw + NWAVE * ii;
                if (row < NN) {
                    const int beg = rfl(rowbeg[row]);
                    const int deg = rfl(counts[row]);
                    const int end = beg + deg;
                    float a[8];
                    #pragma unroll
                    for (int q = 0; q < 8; ++q) a[q] = 0.f;
                    a[0] = b2f(hin[row * 64 + lane]);   // self term

                    if (deg <= 16) {
                        const int safeb = (beg < EE) ? beg : 0;
                        int c[16];
                        #pragma unroll
                        for (int t = 0; t < 16; ++t) {
                            const int jj = (t < deg) ? (beg + t) : safeb;
                            c[t] = rfl(col[jj]);
                        }
                        float hv[16];
                        #pragma unroll
                        for (int t = 0; t < 16; ++t) hv[t] = b2f(hin[c[t] * 64 + lane]);
                        #pragma unroll
                        for (int t = 0; t < 16; ++t) a[t & 7] += (t < deg) ? hv[t] : 0.f;
                    } else {
                        int j = beg;
                        for (; j + 16 <= end; j += 16) {
                            int c[16];
                            #pragma unroll
                            for (int t = 0; t < 16; ++t) c[t] = rfl(col[j + t]);
                            float hv[16];
                            #pragma unroll
                            for (int t = 0; t < 16; ++t) hv[t] = b2f(hin[c[t] * 64 + lane]);
                            #pragma unroll
                            for (int t = 0; t < 16; ++t) a[t & 7] += hv[t];
                        }
                        if (j < end) {
                            int c[16];
                            #pragma unroll
                            for (int t = 0; t < 16; ++t) {
                                const int jj = (j + t < end) ? (j + t) : beg;
                                c[t] = rfl(col[jj]);
                            }
                            float hv[16];
                            #pragma unroll
                            for (int t = 0; t < 16; ++t) hv[t] = b2f(hin[c[t] * 64 + lane]);
                            #pragma unroll
                            for (int t = 0; t < 16; ++t) a[t & 7] += (j + t < end) ? hv[t] : 0.f;
                        }
                    }
                    const float sum = ((a[0] + a[1]) + (a[2] + a[3])) + ((a[4] + a[5]) + (a[6] + a[7]));
                    zbf[row * 64 + lane] = f2b(fmaf(sum, scl, (float)(deg + 1) * sft));
                }
            }
        }
        GSYNC();

        // ---- MFMA MLP: tiles strided over 768 blocks, weights in LDS ----
        {
            const int wave = threadIdx.x >> 6;
            const int quad = lane >> 4;
            const int l15 = lane & 15;

            #pragma unroll
            for (int i2 = 0; i2 < 2; ++i2) {
                const int idx = i2 * 256 + threadIdx.x;
                ((short8*)wlds)[idx] = ((const short8*)wfa)[idx];
                ((short8*)(wlds + 4096))[idx] = ((const short8*)wfb)[idx];
            }
            float biasA[4], biasB[4];
            #pragma unroll
            for (int nt = 0; nt < 4; ++nt) {
                biasA[nt] = ba[nt * 16 + l15];
                biasB[nt] = bb[nt * 16 + l15];
            }
            __syncthreads();   // wlds staged

            for (int tile = blockIdx.x; tile < TILES; tile += NBLK) {
                const int rowbase = tile * 64 + wave * 16;
                const bool valid = rowbase < NN;
                const int arow = valid ? (rowbase + l15) : 0;
                const short8 a0 = *(const short8*)(zbf + arow * 64 + quad * 8);
                const short8 a1 = *(const short8*)(zbf + arow * 64 + 32 + quad * 8);

                f32x4 acc[4];
                #pragma unroll
                for (int nt = 0; nt < 4; ++nt) {
                    f32x4 c = {0.f, 0.f, 0.f, 0.f};
                    c = __builtin_amdgcn_mfma_f32_16x16x32_bf16(
                            a0, *(const short8*)(&wlds[(nt * 64 + lane) * 8]), c, 0, 0, 0);
                    c = __builtin_amdgcn_mfma_f32_16x16x32_bf16(
                            a1, *(const short8*)(&wlds[((4 + nt) * 64 + lane) * 8]), c, 0, 0, 0);
                    acc[nt] = c;
                }
                #pragma unroll
                for (int nt = 0; nt < 4; ++nt)
                    #pragma unroll
                    for (int r = 0; r < 4; ++r)
                        ldsT[wave][quad * 4 + r][nt * 16 + l15] =
                            f2b(fmaxf(acc[nt][r] + biasA[nt], 0.f));

                const short8 y0 = *(const short8*)(&ldsT[wave][l15][quad * 8]);
                const short8 y1 = *(const short8*)(&ldsT[wave][l15][32 + quad * 8]);

                #pragma unroll
                for (int nt = 0; nt < 4; ++nt) {
                    f32x4 c = {0.f, 0.f, 0.f, 0.f};
                    c = __builtin_amdgcn_mfma_f32_16x16x32_bf16(
                            y0, *(const short8*)(&wlds[4096 + (nt * 64 + lane) * 8]), c, 0, 0, 0);
                    c = __builtin_amdgcn_mfma_f32_16x16x32_bf16(
                            y1, *(const short8*)(&wlds[4096 + ((4 + nt) * 64 + lane) * 8]), c, 0, 0, 0);
                    acc[nt] = c;
                }
                #pragma unroll
                for (int nt = 0; nt < 4; ++nt)
                    #pragma unroll
                    for (int r = 0; r < 4; ++r)
                        ldsT[wave][quad * 4 + r][nt * 16 + l15] =
                            f2b(fmaxf(acc[nt][r] + biasB[nt], 0.f));

                // BN partials
                {
                    float s = 0.f, sq = 0.f;
                    if (valid) {
                        #pragma unroll 4
                        for (int r = 0; r < 16; ++r) {
                            const float v = b2f(ldsT[wave][r][lane]);
                            s += v;
                            sq += v * v;
                        }
                    }
                    red[wave * 128 + lane] = s;
                    red[wave * 128 + 64 + lane] = sq;
                }
                __syncthreads();

                if (threadIdx.x < 128) {
                    const float tot = red[threadIdx.x] + red[128 + threadIdx.x] +
                                      red[256 + threadIdx.x] + red[384 + threadIdx.x];
                    atomicAdd(&statsL[(tile & 7) * 128 + threadIdx.x], tot);
                }

                #pragma unroll
                for (int m = 0; m < 4; ++m) {
                    const int g = m * 256 + threadIdx.x;
                    const int r = g >> 4;
                    const int f4 = (g & 15) * 4;
                    const int grow = tile * 64 + r;
                    if (grow < NN)
                        *(ushort4*)(tout + grow * 64 + f4) =
                            *(const ushort4*)(&ldsT[r >> 4][r & 15][f4]);
                }
                __syncthreads();   // protect ldsT before next strided tile
            }
        }
        GSYNC();
    }

    // ================= pool (BN-3 finalize folded) =================
    {
        float s = 0.f, sq = 0.f;
        const float* st3 = stats + 2048;
        #pragma unroll
        for (int k = 0; k < 8; ++k) {
            s += st3[k * 128 + lane];
            sq += st3[k * 128 + 64 + lane];
        }
        const float mean = s * (1.0f / NN);
        const float var = sq * (1.0f / NN) - mean * mean;
        const float scl = p.g3[lane] * rsqrtf(var + 1e-5f);
        const float sft = p.be3[lane] - mean * scl;

        const int wv = gtid >> 6;
        if (wv < TILES) {
            const int r0 = wv * 64;
            const int r1 = min(r0 + 64, NN);
            int gprev = p.batch[r0];
            float acc = 0.f;
            for (int r = r0; r < r1; ++r) {
                const int g = p.batch[r];
                if (g != gprev) {
                    __hip_atomic_fetch_add(&xpool[gprev * 64 + lane], acc,
                                           __ATOMIC_RELAXED, __HIP_MEMORY_SCOPE_AGENT);
                    acc = 0.f;
                    gprev = g;
                }
                acc += fmaf(b2f(t0[r * 64 + lane]), scl, sft);
            }
            __hip_atomic_fetch_add(&xpool[gprev * 64 + lane], acc,
                                   __ATOMIC_RELAXED, __HIP_MEMORY_SCOPE_AGENT);
        }
    }
    GSYNC();

    // ================= head: 2 groups per block, blocks 0..255 =================
    if (blockIdx.x < GG / 2) {
        float* hxp  = (float*)smraw;         // [2][64]
        float* hmid = (float*)smraw + 128;   // [2][128]
        const int half = threadIdx.x >> 7;
        const int tt = threadIdx.x & 127;
        const int g = blockIdx.x * 2 + half;
        if (tt < 64) hxp[half * 64 + tt] = xpool[g * 64 + tt];
        __syncthreads();
        float acc = p.blin0[tt];
        #pragma unroll 8
        for (int k = 0; k < 64; ++k) acc = fmaf(hxp[half * 64 + k], p.wlin0[k * 128 + tt], acc);
        hmid[half * 128 + tt] = acc;
        __syncthreads();
        if (tt < 64) {
            float a2 = p.bfc1[tt];
            #pragma unroll 8
            for (int k = 0; k < 128; ++k) a2 = fmaf(hmid[half * 128 + k], p.wfc1[k * 64 + tt], a2);
            p.out[g * 64 + tt] = fmaxf(a2, 0.f);
        }
    }
#undef GSYNC
}

extern "C" void kernel_launch(void* const* d_in, const int* in_sizes, int n_in,
                              void* d_out, int out_size, void* d_ws, size_t ws_size,
                              hipStream_t stream) {
    Params p;
    p.x     = (const float*)d_in[0];
    p.ei    = (const int*)d_in[1];
    p.batch = (const int*)d_in[2];
    p.w1a = (const float*)d_in[3];  p.b1a = (const float*)d_in[4];
    p.w1b = (const float*)d_in[5];  p.b1b = (const float*)d_in[6];
    p.g1  = (const float*)d_in[7];  p.be1 = (const float*)d_in[8];
    p.w2a = (const float*)d_in[9];  p.b2a = (const float*)d_in[10];
    p.w2b = (const float*)d_in[11]; p.b2b = (const float*)d_in[12];
    p.g2  = (const float*)d_in[13]; p.be2 = (const float*)d_in[14];
    p.w3a = (const float*)d_in[15]; p.b3a = (const float*)d_in[16];
    p.w3b = (const float*)d_in[17]; p.b3b = (const float*)d_in[18];
    p.g3  = (const float*)d_in[19]; p.be3 = (const float*)d_in[20];
    p.wlin0 = (const float*)d_in[21]; p.blin0 = (const float*)d_in[22];
    p.wfc1  = (const float*)d_in[23]; p.bfc1  = (const float*)d_in[24];
    p.out = (float*)d_out;
    p.ws  = d_ws;

    int* gctr_bar = (int*)d_ws + 150000;   // gctr(16) + bar(16)
    init_kernel<<<1, 64, 0, stream>>>(gctr_bar);
    mega_kernel<<<NBLK, NTHR, 0, stream>>>(p);
}

// Round 7
// 995.305 us; speedup vs baseline: 1.9265x; 1.9265x over previous
//
#include <hip/hip_runtime.h>

#define NN 50000
#define EE 800000
#define GG 512
#define TILES 782          // ceil(NN/64)
#define NBLK 768           // 3 blocks/CU needed; capacity 5/CU (LDS) -> co-resident
#define NTHR 256
#define NTOT (NBLK * NTHR) // 196608 threads
#define NWAVE (NTOT / 64)  // 3072 waves

typedef __attribute__((ext_vector_type(8))) short short8;
typedef __attribute__((ext_vector_type(4))) float f32x4;

// ---- bf16 helpers ----
__device__ __forceinline__ float b2f(unsigned short u) {
    union { unsigned int i; float f; } c;
    c.i = ((unsigned int)u) << 16;
    return c.f;
}
__device__ __forceinline__ unsigned short f2b(float f) {
    union { float f; unsigned int i; } c;
    c.f = f;
    const unsigned int r = c.i + 0x7FFFu + ((c.i >> 16) & 1u);  // rne
    return (unsigned short)(r >> 16);
}
__device__ __forceinline__ int rfl(int v) { return __builtin_amdgcn_readfirstlane(v); }

struct Params {
    const float* x; const int* ei; const int* batch;
    const float* w1a; const float* b1a; const float* w1b; const float* b1b; const float* g1; const float* be1;
    const float* w2a; const float* b2a; const float* w2b; const float* b2b; const float* g2; const float* be2;
    const float* w3a; const float* b3a; const float* w3b; const float* b3b; const float* g3; const float* be3;
    const float* wlin0; const float* blin0; const float* wfc1; const float* bfc1;
    float* out; void* ws;
};

// Zero the barrier + global counters each replay (workspace is re-poisoned
// between harness iterations). 1 block, launched before the mega kernel.
__global__ void init_kernel(int* bar) {
    if (threadIdx.x < 32) bar[threadIdx.x] = 0;
}

// ===========================================================================
// Persistent mega-kernel, regular launch. Round-7 barrier fix: the round-6
// version used ACQUIRE loads in the poll loop + __threadfence -> buffer_inv
// (full L1/L2 invalidate) every ~200ns per poller => 1825us. Correct form:
// one RELEASE fence (wbL2) before the arrive-add, RELAXED polls (fabric
// atomic reads, no cache-inv), one ACQUIRE fence (inv) after exit.
// ===========================================================================
__global__ __launch_bounds__(256, 4) void mega_kernel(Params p) {
    // ---- workspace layout ----
    int* ibase   = (int*)p.ws;
    int* counts  = ibase;            // 50000 (= deg[])
    int* rowbeg  = ibase + 50000;    // 50000
    int* cursor  = ibase + 100000;   // 50000
    int* gctr    = ibase + 150000;   // 16 ints (zeroed by init_kernel)
    int* bar     = ibase + 150016;   // 16 ints (zeroed by init_kernel)
    int* col     = ibase + 150032;   // 800000 -> end 950032, pad to 950048
    float* fbase = (float*)p.ws + 950048;
    float* stats = fbase;            // 3 x 1024
    float* xpool = stats + 3072;     // 32768
    unsigned short* zbf   = (unsigned short*)(fbase + 35840);  // NN*64
    unsigned short* xbf   = zbf + 3200000;
    unsigned short* t0    = xbf + 3200000;
    unsigned short* t1    = t0 + 3200000;
    unsigned short* wfrag = t1 + 3200000;   // 6 x 4096 bf16

    __shared__ __align__(16) unsigned char smraw[27648];

    const int gtid = blockIdx.x * NTHR + threadIdx.x;
    const int lane = threadIdx.x & 63;

    int bphase = 0;
#define GSYNC() do {                                                           \
        __syncthreads();                                                       \
        ++bphase;                                                              \
        if (threadIdx.x == 0) {                                                \
            __builtin_amdgcn_fence(__ATOMIC_RELEASE, "agent");                 \
            __hip_atomic_fetch_add(bar, 1, __ATOMIC_RELAXED,                   \
                                   __HIP_MEMORY_SCOPE_AGENT);                  \
            int spins = 0;                                                     \
            while (__hip_atomic_load(bar, __ATOMIC_RELAXED,                    \
                                     __HIP_MEMORY_SCOPE_AGENT)                 \
                   < bphase * NBLK) {                                          \
                __builtin_amdgcn_s_sleep(8);                                   \
                if (++spins > (1 << 17)) break;                                \
            }                                                                  \
            __builtin_amdgcn_fence(__ATOMIC_ACQUIRE, "agent");                 \
        }                                                                      \
        __syncthreads();                                                       \
    } while (0)

    // ================= P0: prep =================
    for (int i = gtid; i < 800000; i += NTOT) {
        const float4 v = ((const float4*)p.x)[i];
        ushort4 o;
        o.x = f2b(v.x); o.y = f2b(v.y); o.z = f2b(v.z); o.w = f2b(v.w);
        ((ushort4*)xbf)[i] = o;
    }
    for (int i = gtid; i < 12500; i += NTOT) ((int4*)counts)[i] = make_int4(0, 0, 0, 0);
    for (int i = gtid; i < 8960; i += NTOT) ((float4*)stats)[i] = make_float4(0.f, 0.f, 0.f, 0.f);
    if (blockIdx.x >= NBLK - 6) {   // weight swizzle: fp32 [k][n] -> B-frag order
        const int wi = blockIdx.x - (NBLK - 6);
        const float* w = (wi == 0) ? p.w1a : (wi == 1) ? p.w1b : (wi == 2) ? p.w2a
                       : (wi == 3) ? p.w2b : (wi == 4) ? p.w3a : p.w3b;
        unsigned short* o = wfrag + wi * 4096;
        #pragma unroll
        for (int it = 0; it < 2; ++it) {
            const int idx = it * 256 + threadIdx.x;
            const int fid = idx >> 6, ln = idx & 63;
            const int kt = fid >> 2, nt = fid & 3;
            const int kbase = kt * 32 + (ln >> 4) * 8;
            const int n = nt * 16 + (ln & 15);
            #pragma unroll
            for (int j = 0; j < 8; ++j)
                o[idx * 8 + j] = f2b(w[(kbase + j) * 64 + n]);
        }
    }
    GSYNC();

    // ================= P1: histogram =================
    for (int e = gtid; e < EE; e += NTOT) atomicAdd(&counts[p.ei[EE + e]], 1);
    GSYNC();

    // ================= P2: alloc (order-free rowbeg via wave-agg atomics) ====
    {
        const int gw = gtid >> 6;
        if (gw < TILES) {
            const int r = gw * 64 + lane;
            const int cnt = (r < NN) ? counts[r] : 0;
            int incl = cnt;
            #pragma unroll
            for (int off = 1; off < 64; off <<= 1) {
                const int tv = __shfl_up(incl, off);
                if (lane >= off) incl += tv;
            }
            const int tot = __shfl(incl, 63);
            int base = 0;
            if (lane == 63) base = atomicAdd(gctr, tot);
            base = __shfl(base, 63);
            if (r < NN) {
                const int b0 = base + incl - cnt;
                rowbeg[r] = b0;
                cursor[r] = b0;
            }
        }
    }
    GSYNC();

    // ================= P3: fill (8 classes x 96 chunk-blocks) =================
    {
        const int cls = blockIdx.x & 7;
        const int idx = blockIdx.x >> 3;            // 0..95
        for (int e = idx * NTHR + threadIdx.x; e < EE; e += 96 * NTHR) {
            const int dst = p.ei[EE + e];
            if (dst / 6250 == cls) {
                const int pos = atomicAdd(&cursor[dst], 1);
                col[pos] = p.ei[e];
            }
        }
    }
    GSYNC();

    // ================= 3 GIN layers =================
    unsigned short* wlds = (unsigned short*)smraw;                                 // 8192 ush
    unsigned short (*ldsT)[16][72] = (unsigned short (*)[16][72])(smraw + 16384);  // 4x16x72
    float* red = (float*)(smraw + 16384 + 9216);                                   // 512 f

    for (int l = 0; l < 3; ++l) {
        const float* ba = (l == 0) ? p.b1a : (l == 1) ? p.b2a : p.b3a;
        const float* bb = (l == 0) ? p.b1b : (l == 1) ? p.b2b : p.b3b;
        const float* gp = (l == 1) ? p.g1 : p.g2;
        const float* bp = (l == 1) ? p.be1 : p.be2;
        const unsigned short* hin = (l == 0) ? xbf : (l == 1) ? t0 : t1;
        unsigned short* tout = (l == 1) ? t1 : t0;
        const unsigned short* wfa = wfrag + (l * 2 + 0) * 4096;
        const unsigned short* wfb = wfrag + (l * 2 + 1) * 4096;
        float* statsL = stats + l * 1024;
        const float* statsP = stats + (l ? (l - 1) : 0) * 1024;

        // ---- gather: 3072 waves, 17 strided rows each ----
        {
            float scl = 1.0f, sft = 0.0f;
            if (l > 0) {   // folded BN finalize of previous layer
                float s = 0.f, sq = 0.f;
                #pragma unroll
                for (int k = 0; k < 8; ++k) {
                    s += statsP[k * 128 + lane];
                    sq += statsP[k * 128 + 64 + lane];
                }
                const float mean = s * (1.0f / NN);
                const float var = sq * (1.0f / NN) - mean * mean;
                scl = gp[lane] * rsqrtf(var + 1e-5f);
                sft = bp[lane] - mean * scl;
            }
            const int gw = gtid >> 6;
            for (int ii = 0; ii < 17; ++ii) {
                const int row = gw + NWAVE * ii;
                if (row < NN) {
                    const int beg = rfl(rowbeg[row]);
                    const int deg = rfl(counts[row]);
                    const int end = beg + deg;
                    float a[8];
                    #pragma unroll
                    for (int q = 0; q < 8; ++q) a[q] = 0.f;
                    a[0] = b2f(hin[row * 64 + lane]);   // self term

                    if (deg <= 16) {
                        const int safeb = (beg < EE) ? beg : 0;
                        int c[16];
                        #pragma unroll
                        for (int t = 0; t < 16; ++t) {
                            const int jj = (t < deg) ? (beg + t) : safeb;
                            c[t] = rfl(col[jj]);
                        }
                        float hv[16];
                        #pragma unroll
                        for (int t = 0; t < 16; ++t) hv[t] = b2f(hin[c[t] * 64 + lane]);
                        #pragma unroll
                        for (int t = 0; t < 16; ++t) a[t & 7] += (t < deg) ? hv[t] : 0.f;
                    } else {
                        int j = beg;
                        for (; j + 16 <= end; j += 16) {
                            int c[16];
                            #pragma unroll
                            for (int t = 0; t < 16; ++t) c[t] = rfl(col[j + t]);
                            float hv[16];
                            #pragma unroll
                            for (int t = 0; t < 16; ++t) hv[t] = b2f(hin[c[t] * 64 + lane]);
                            #pragma unroll
                            for (int t = 0; t < 16; ++t) a[t & 7] += hv[t];
                        }
                        if (j < end) {
                            int c[16];
                            #pragma unroll
                            for (int t = 0; t < 16; ++t) {
                                const int jj = (j + t < end) ? (j + t) : beg;
                                c[t] = rfl(col[jj]);
                            }
                            float hv[16];
                            #pragma unroll
                            for (int t = 0; t < 16; ++t) hv[t] = b2f(hin[c[t] * 64 + lane]);
                            #pragma unroll
                            for (int t = 0; t < 16; ++t) a[t & 7] += (j + t < end) ? hv[t] : 0.f;
                        }
                    }
                    const float sum = ((a[0] + a[1]) + (a[2] + a[3])) + ((a[4] + a[5]) + (a[6] + a[7]));
                    zbf[row * 64 + lane] = f2b(fmaf(sum, scl, (float)(deg + 1) * sft));
                }
            }
        }
        GSYNC();

        // ---- MFMA MLP: tiles strided over 768 blocks, weights in LDS ----
        {
            const int wave = threadIdx.x >> 6;
            const int quad = lane >> 4;
            const int l15 = lane & 15;

            #pragma unroll
            for (int i2 = 0; i2 < 2; ++i2) {
                const int idx = i2 * 256 + threadIdx.x;
                ((short8*)wlds)[idx] = ((const short8*)wfa)[idx];
                ((short8*)(wlds + 4096))[idx] = ((const short8*)wfb)[idx];
            }
            float biasA[4], biasB[4];
            #pragma unroll
            for (int nt = 0; nt < 4; ++nt) {
                biasA[nt] = ba[nt * 16 + l15];
                biasB[nt] = bb[nt * 16 + l15];
            }
            __syncthreads();   // wlds staged

            for (int tile = blockIdx.x; tile < TILES; tile += NBLK) {
                const int rowbase = tile * 64 + wave * 16;
                const bool valid = rowbase < NN;
                const int arow = valid ? (rowbase + l15) : 0;
                const short8 a0 = *(const short8*)(zbf + arow * 64 + quad * 8);
                const short8 a1 = *(const short8*)(zbf + arow * 64 + 32 + quad * 8);

                f32x4 acc[4];
                #pragma unroll
                for (int nt = 0; nt < 4; ++nt) {
                    f32x4 c = {0.f, 0.f, 0.f, 0.f};
                    c = __builtin_amdgcn_mfma_f32_16x16x32_bf16(
                            a0, *(const short8*)(&wlds[(nt * 64 + lane) * 8]), c, 0, 0, 0);
                    c = __builtin_amdgcn_mfma_f32_16x16x32_bf16(
                            a1, *(const short8*)(&wlds[((4 + nt) * 64 + lane) * 8]), c, 0, 0, 0);
                    acc[nt] = c;
                }
                #pragma unroll
                for (int nt = 0; nt < 4; ++nt)
                    #pragma unroll
                    for (int r = 0; r < 4; ++r)
                        ldsT[wave][quad * 4 + r][nt * 16 + l15] =
                            f2b(fmaxf(acc[nt][r] + biasA[nt], 0.f));

                const short8 y0 = *(const short8*)(&ldsT[wave][l15][quad * 8]);
                const short8 y1 = *(const short8*)(&ldsT[wave][l15][32 + quad * 8]);

                #pragma unroll
                for (int nt = 0; nt < 4; ++nt) {
                    f32x4 c = {0.f, 0.f, 0.f, 0.f};
                    c = __builtin_amdgcn_mfma_f32_16x16x32_bf16(
                            y0, *(const short8*)(&wlds[4096 + (nt * 64 + lane) * 8]), c, 0, 0, 0);
                    c = __builtin_amdgcn_mfma_f32_16x16x32_bf16(
                            y1, *(const short8*)(&wlds[4096 + ((4 + nt) * 64 + lane) * 8]), c, 0, 0, 0);
                    acc[nt] = c;
                }
                #pragma unroll
                for (int nt = 0; nt < 4; ++nt)
                    #pragma unroll
                    for (int r = 0; r < 4; ++r)
                        ldsT[wave][quad * 4 + r][nt * 16 + l15] =
                            f2b(fmaxf(acc[nt][r] + biasB[nt], 0.f));

                // BN partials
                {
                    float s = 0.f, sq = 0.f;
                    if (valid) {
                        #pragma unroll 4
                        for (int r = 0; r < 16; ++r) {
                            const float v = b2f(ldsT[wave][r][lane]);
                            s += v;
                            sq += v * v;
                        }
                    }
                    red[wave * 128 + lane] = s;
                    red[wave * 128 + 64 + lane] = sq;
                }
                __syncthreads();

                if (threadIdx.x < 128) {
                    const float tot = red[threadIdx.x] + red[128 + threadIdx.x] +
                                      red[256 + threadIdx.x] + red[384 + threadIdx.x];
                    atomicAdd(&statsL[(tile & 7) * 128 + threadIdx.x], tot);
                }

                #pragma unroll
                for (int m = 0; m < 4; ++m) {
                    const int g = m * 256 + threadIdx.x;
                    const int r = g >> 4;
                    const int f4 = (g & 15) * 4;
                    const int grow = tile * 64 + r;
                    if (grow < NN)
                        *(ushort4*)(tout + grow * 64 + f4) =
                            *(const ushort4*)(&ldsT[r >> 4][r & 15][f4]);
                }
                __syncthreads();   // protect ldsT before next strided tile
            }
        }
        GSYNC();
    }

    // ================= pool (BN-3 finalize folded) =================
    {
        float s = 0.f, sq = 0.f;
        const float* st3 = stats + 2048;
        #pragma unroll
        for (int k = 0; k < 8; ++k) {
            s += st3[k * 128 + lane];
            sq += st3[k * 128 + 64 + lane];
        }
        const float mean = s * (1.0f / NN);
        const float var = sq * (1.0f / NN) - mean * mean;
        const float scl = p.g3[lane] * rsqrtf(var + 1e-5f);
        const float sft = p.be3[lane] - mean * scl;

        const int wv = gtid >> 6;
        if (wv < TILES) {
            const int r0 = wv * 64;
            const int r1 = min(r0 + 64, NN);
            int gprev = p.batch[r0];
            float acc = 0.f;
            for (int r = r0; r < r1; ++r) {
                const int g = p.batch[r];
                if (g != gprev) {
                    __hip_atomic_fetch_add(&xpool[gprev * 64 + lane], acc,
                                           __ATOMIC_RELAXED, __HIP_MEMORY_SCOPE_AGENT);
                    acc = 0.f;
                    gprev = g;
                }
                acc += fmaf(b2f(t0[r * 64 + lane]), scl, sft);
            }
            __hip_atomic_fetch_add(&xpool[gprev * 64 + lane], acc,
                                   __ATOMIC_RELAXED, __HIP_MEMORY_SCOPE_AGENT);
        }
    }
    GSYNC();

    // ================= head: 2 groups per block, blocks 0..255 =================
    if (blockIdx.x < GG / 2) {
        float* hxp  = (float*)smraw;         // [2][64]
        float* hmid = (float*)smraw + 128;   // [2][128]
        const int half = threadIdx.x >> 7;
        const int tt = threadIdx.x & 127;
        const int g = blockIdx.x * 2 + half;
        if (tt < 64) hxp[half * 64 + tt] = xpool[g * 64 + tt];
        __syncthreads();
        float acc = p.blin0[tt];
        #pragma unroll 8
        for (int k = 0; k < 64; ++k) acc = fmaf(hxp[half * 64 + k], p.wlin0[k * 128 + tt], acc);
        hmid[half * 128 + tt] = acc;
        __syncthreads();
        if (tt < 64) {
            float a2 = p.bfc1[tt];
            #pragma unroll 8
            for (int k = 0; k < 128; ++k) a2 = fmaf(hmid[half * 128 + k], p.wfc1[k * 64 + tt], a2);
            p.out[g * 64 + tt] = fmaxf(a2, 0.f);
        }
    }
#undef GSYNC
}

extern "C" void kernel_launch(void* const* d_in, const int* in_sizes, int n_in,
                              void* d_out, int out_size, void* d_ws, size_t ws_size,
                              hipStream_t stream) {
    Params p;
    p.x     = (const float*)d_in[0];
    p.ei    = (const int*)d_in[1];
    p.batch = (const int*)d_in[2];
    p.w1a = (const float*)d_in[3];  p.b1a = (const float*)d_in[4];
    p.w1b = (const float*)d_in[5];  p.b1b = (const float*)d_in[6];
    p.g1  = (const float*)d_in[7];  p.be1 = (const float*)d_in[8];
    p.w2a = (const float*)d_in[9];  p.b2a = (const float*)d_in[10];
    p.w2b = (const float*)d_in[11]; p.b2b = (const float*)d_in[12];
    p.g2  = (const float*)d_in[13]; p.be2 = (const float*)d_in[14];
    p.w3a = (const float*)d_in[15]; p.b3a = (const float*)d_in[16];
    p.w3b = (const float*)d_in[17]; p.b3b = (const float*)d_in[18];
    p.g3  = (const float*)d_in[19]; p.be3 = (const float*)d_in[20];
    p.wlin0 = (const float*)d_in[21]; p.blin0 = (const float*)d_in[22];
    p.wfc1  = (const float*)d_in[23]; p.bfc1  = (const float*)d_in[24];
    p.out = (float*)d_out;
    p.ws  = d_ws;

    int* gctr_bar = (int*)d_ws + 150000;   // gctr(16) + bar(16)
    init_kernel<<<1, 64, 0, stream>>>(gctr_bar);
    mega_kernel<<<NBLK, NTHR, 0, stream>>>(p);
}

// Round 8
// 536.189 us; speedup vs baseline: 3.5761x; 1.8563x over previous
//
#include <hip/hip_runtime.h>

#define NN 50000
#define EE 800000
#define GG 512
#define TILES 782          // ceil(NN/64)
#define NBLK 784           // >= TILES, 8*98; capacity 4 blocks/CU (LDS) = 1024
#define NTHR 256
#define NTOT (NBLK * NTHR) // 200704 threads

typedef __attribute__((ext_vector_type(8))) short short8;
typedef __attribute__((ext_vector_type(4))) float f32x4;

__device__ __forceinline__ float b2f(unsigned short u) {
    union { unsigned int i; float f; } c;
    c.i = ((unsigned int)u) << 16;
    return c.f;
}
__device__ __forceinline__ unsigned short f2b(float f) {
    union { float f; unsigned int i; } c;
    c.f = f;
    const unsigned int r = c.i + 0x7FFFu + ((c.i >> 16) & 1u);  // rne
    return (unsigned short)(r >> 16);
}
__device__ __forceinline__ int rfl(int v) { return __builtin_amdgcn_readfirstlane(v); }

__device__ __forceinline__ int lowb(const int* b, int v) {
    int lo = 0, hi = NN;
    while (lo < hi) { const int m = (lo + hi) >> 1; if (b[m] < v) lo = m + 1; else hi = m; }
    return lo;
}

struct Params {
    const float* x; const int* ei; const int* batch;
    const float* w1a; const float* b1a; const float* w1b; const float* b1b; const float* g1; const float* be1;
    const float* w2a; const float* b2a; const float* w2b; const float* b2b; const float* g2; const float* be2;
    const float* w3a; const float* b3a; const float* w3b; const float* b3b; const float* g3; const float* be3;
    const float* wlin0; const float* blin0; const float* wfc1; const float* bfc1;
    float* out; void* ws;
};

// ctrl[0]=gbar, [1..8]=xcnt, [9..16]=xarr, [17..24]=go, [25]=gctr
__global__ void init_kernel(int* ctrl) {
    if (threadIdx.x < 32) ctrl[threadIdx.x] = 0;
}

// ===========================================================================
// Persistent mega-kernel, regular launch. Round-8 barrier protocol:
//  - per-XCD leader election via s_getreg(HW_REG_XCC_ID) (imm 6164: id=20,
//    offset 0, width 4; HW-verified on MI355X).
//  - only XCD leaders (8, not 768) issue the RELEASE wb, and only at the 3
//    barriers with normal-store -> cross-XCD-read edges.
//  - NO acquire-inv anywhere: fabric-atomic-only arrays (counts/cursor/
//    stats/xpool, incl. their zeroing) never have L2 copies; bulk arrays
//    (xbf/col/rowbeg/t0/t1/wfrag) are first-read after final update + wb,
//    so reader L2s allocate fresh from IF$.
// ===========================================================================
__global__ __launch_bounds__(256, 4) void mega_kernel(Params p) {
    int* ibase   = (int*)p.ws;
    int* counts  = ibase;            // 50000 (= deg[]), fabric-only writes
    int* rowbeg  = ibase + 50000;    // 50000, normal stores (wb'd at B3)
    int* cursor  = ibase + 100000;   // 50000, fabric-only
    int* ctrl    = ibase + 150000;   // 32 ints (init_kernel zeroes)
    int* col     = ibase + 150032;   // 800000
    float* fbase = (float*)p.ws + 950048;
    float* stats = fbase;            // 3 x 1024, fabric-only
    float* xpool = stats + 3072;     // 32768, fabric-only (raw pre-BN sums)
    unsigned short* zbf   = (unsigned short*)(fbase + 35840);  // unused (kept for layout)
    unsigned short* xbf   = zbf + 3200000;
    unsigned short* t0    = xbf + 3200000;
    unsigned short* t1    = t0 + 3200000;
    unsigned short* wfrag = t1 + 3200000;   // 6 x 4096 bf16

    __shared__ __align__(16) unsigned char smraw[36864];
    unsigned short* wlds = (unsigned short*)smraw;                                  // 16384 B
    unsigned short (*ztile)[72] = (unsigned short (*)[72])(smraw + 16384);          // 64x72x2
    unsigned short (*ldsT)[16][72] = (unsigned short (*)[16][72])(smraw + 25600);   // 4x16x72x2
    float* red = (float*)(smraw + 34816);                                           // 512 f

    const int gtid = blockIdx.x * NTHR + threadIdx.x;
    const int lane = threadIdx.x & 63;
    const int wave = threadIdx.x >> 6;
    const int quad = lane >> 4;
    const int l15 = lane & 15;

    int myxcd = 0, xcdN = 0, nxcd = 0;

    // ================= P0: prep + registration =================
    if (threadIdx.x == 0) {
        myxcd = __builtin_amdgcn_s_getreg(6164) & 7;   // HW_REG_XCC_ID
        __hip_atomic_fetch_add(&ctrl[1 + myxcd], 1, __ATOMIC_RELAXED, __HIP_MEMORY_SCOPE_AGENT);
        __builtin_amdgcn_s_waitcnt(0);                 // registration visible before arrive
    }
    for (int i = gtid; i < 800000; i += NTOT) {
        const float4 v = ((const float4*)p.x)[i];
        ushort4 o;
        o.x = f2b(v.x); o.y = f2b(v.y); o.z = f2b(v.z); o.w = f2b(v.w);
        ((ushort4*)xbf)[i] = o;
    }
    for (int i = gtid; i < 50000; i += NTOT)
        __hip_atomic_store(&counts[i], 0, __ATOMIC_RELAXED, __HIP_MEMORY_SCOPE_AGENT);
    for (int i = gtid; i < 35840; i += NTOT)   // stats(3072) + xpool(32768)
        __hip_atomic_store(&fbase[i], 0.0f, __ATOMIC_RELAXED, __HIP_MEMORY_SCOPE_AGENT);
    if (blockIdx.x >= NBLK - 6) {   // weight swizzle: fp32 [k][n] -> B-frag order
        const int wi = blockIdx.x - (NBLK - 6);
        const float* w = (wi == 0) ? p.w1a : (wi == 1) ? p.w1b : (wi == 2) ? p.w2a
                       : (wi == 3) ? p.w2b : (wi == 4) ? p.w3a : p.w3b;
        unsigned short* o = wfrag + wi * 4096;
        #pragma unroll
        for (int it = 0; it < 2; ++it) {
            const int idx = it * 256 + threadIdx.x;
            const int fid = idx >> 6, ln = idx & 63;
            const int kt = fid >> 2, nt = fid & 3;
            const int kbase = kt * 32 + (ln >> 4) * 8;
            const int n = nt * 16 + (ln & 15);
            #pragma unroll
            for (int j = 0; j < 8; ++j)
                o[idx * 8 + j] = f2b(w[(kbase + j) * 64 + n]);
        }
    }

    // ---- B1: full counting barrier (also completes registration) ----
    __syncthreads();
    if (threadIdx.x == 0) {
        __hip_atomic_fetch_add(&ctrl[0], 1, __ATOMIC_RELAXED, __HIP_MEMORY_SCOPE_AGENT);
        int sp = 0;
        while (__hip_atomic_load(&ctrl[0], __ATOMIC_RELAXED, __HIP_MEMORY_SCOPE_AGENT) < NBLK) {
            __builtin_amdgcn_s_sleep(4);
            if (++sp > (1 << 18)) break;
        }
        xcdN = __hip_atomic_load(&ctrl[1 + myxcd], __ATOMIC_RELAXED, __HIP_MEMORY_SCOPE_AGENT);
        nxcd = 0;
        #pragma unroll
        for (int x = 0; x < 8; ++x)
            nxcd += (__hip_atomic_load(&ctrl[1 + x], __ATOMIC_RELAXED, __HIP_MEMORY_SCOPE_AGENT) > 0);
        __builtin_amdgcn_fence(__ATOMIC_ACQUIRE, "workgroup");
    }
    __syncthreads();

    // ---- leader barrier macro: k-th post-B1 barrier, WB = compile-time ----
#define LBAR(k, WB) do {                                                         \
        __syncthreads();                                                         \
        if (threadIdx.x == 0) {                                                  \
            const int r_ = __hip_atomic_fetch_add(&ctrl[9 + myxcd], 1,           \
                               __ATOMIC_RELAXED, __HIP_MEMORY_SCOPE_AGENT);      \
            if (r_ == (k) * xcdN - 1) {                                          \
                if (WB) {                                                        \
                    __builtin_amdgcn_fence(__ATOMIC_RELEASE, "agent");           \
                    __builtin_amdgcn_s_waitcnt(0);                               \
                }                                                                \
                __hip_atomic_fetch_add(&ctrl[0], 1, __ATOMIC_RELAXED,            \
                                       __HIP_MEMORY_SCOPE_AGENT);                \
                const int tgt_ = NBLK + (k) * nxcd;                              \
                int sp_ = 0;                                                     \
                while (__hip_atomic_load(&ctrl[0], __ATOMIC_RELAXED,             \
                                         __HIP_MEMORY_SCOPE_AGENT) < tgt_) {     \
                    __builtin_amdgcn_s_sleep(4);                                 \
                    if (++sp_ > (1 << 18)) break;                                \
                }                                                                \
                __hip_atomic_store(&ctrl[17 + myxcd], (k), __ATOMIC_RELAXED,     \
                                   __HIP_MEMORY_SCOPE_AGENT);                    \
            } else {                                                             \
                int sp_ = 0;                                                     \
                while (__hip_atomic_load(&ctrl[17 + myxcd], __ATOMIC_RELAXED,    \
                                         __HIP_MEMORY_SCOPE_AGENT) < (k)) {      \
                    __builtin_amdgcn_s_sleep(4);                                 \
                    if (++sp_ > (1 << 18)) break;                                \
                }                                                                \
            }                                                                    \
            __builtin_amdgcn_fence(__ATOMIC_ACQUIRE, "workgroup");               \
        }                                                                        \
        __syncthreads();                                                         \
    } while (0)

    // ================= P1: histogram (fabric RMW) =================
    for (int e = gtid; e < EE; e += NTOT) atomicAdd(&counts[p.ei[EE + e]], 1);
    LBAR(1, 0);

    // ================= P2: alloc (order-free rowbeg) =================
    {
        const int gw = gtid >> 6;
        if (gw < TILES) {
            const int r = gw * 64 + lane;
            const int cnt = (r < NN) ? counts[r] : 0;   // first normal read, post-final
            int incl = cnt;
            #pragma unroll
            for (int off = 1; off < 64; off <<= 1) {
                const int tv = __shfl_up(incl, off);
                if (lane >= off) incl += tv;
            }
            const int tot = __shfl(incl, 63);
            int base = 0;
            if (lane == 63)
                base = __hip_atomic_fetch_add(&ctrl[25], tot, __ATOMIC_RELAXED,
                                              __HIP_MEMORY_SCOPE_AGENT);
            base = __shfl(base, 63);
            if (r < NN) {
                const int b0 = base + incl - cnt;
                rowbeg[r] = b0;                          // normal store (wb at B3)
                __hip_atomic_store(&cursor[r], b0, __ATOMIC_RELAXED,
                                   __HIP_MEMORY_SCOPE_AGENT);   // fabric (P3 RMW)
            }
        }
    }
    LBAR(2, 0);

    // ================= P3: fill (8 classes x 98 chunk-blocks) =================
    {
        const int cls = blockIdx.x & 7;
        for (int e = (blockIdx.x >> 3) * NTHR + threadIdx.x; e < EE; e += 98 * NTHR) {
            const int dst = p.ei[EE + e];
            if (dst / 6250 == cls) {
                const int pos = atomicAdd(&cursor[dst], 1);
                col[pos] = p.ei[e];
            }
        }
    }
    LBAR(3, 1);   // WB: col, rowbeg, xbf, wfrag become cross-XCD-readable

    // ================= 3 fused GIN layers =================
    for (int l = 0; l < 3; ++l) {
        const float* ba = (l == 0) ? p.b1a : (l == 1) ? p.b2a : p.b3a;
        const float* bb = (l == 0) ? p.b1b : (l == 1) ? p.b2b : p.b3b;
        const float* gp = (l == 1) ? p.g1 : p.g2;
        const float* bp = (l == 1) ? p.be1 : p.be2;
        const unsigned short* hin = (l == 0) ? xbf : (l == 1) ? t0 : t1;
        unsigned short* tout = (l == 1) ? t1 : t0;
        const unsigned short* wfa = wfrag + (l * 2 + 0) * 4096;
        const unsigned short* wfb = wfrag + (l * 2 + 1) * 4096;
        float* statsL = stats + l * 1024;
        const float* statsP = stats + (l ? (l - 1) : 0) * 1024;

        const int tile = blockIdx.x;
        if (tile < TILES) {
            // stage weights -> LDS
            #pragma unroll
            for (int i2 = 0; i2 < 2; ++i2) {
                const int idx = i2 * 256 + threadIdx.x;
                ((short8*)wlds)[idx] = ((const short8*)wfa)[idx];
                ((short8*)(wlds + 4096))[idx] = ((const short8*)wfb)[idx];
            }
            // BN finalize of previous layer (stats: fabric-written, first normal read)
            float scl = 1.0f, sft = 0.0f;
            if (l > 0) {
                float s = 0.f, sq = 0.f;
                #pragma unroll
                for (int k = 0; k < 8; ++k) {
                    s += statsP[k * 128 + lane];
                    sq += statsP[k * 128 + 64 + lane];
                }
                const float mean = s * (1.0f / NN);
                const float var = sq * (1.0f / NN) - mean * mean;
                scl = gp[lane] * rsqrtf(var + 1e-5f);
                sft = bp[lane] - mean * scl;
            }
            float biasA[4], biasB[4];
            #pragma unroll
            for (int nt = 0; nt < 4; ++nt) {
                biasA[nt] = ba[nt * 16 + l15];
                biasB[nt] = bb[nt * 16 + l15];
            }

            // ---- gather this wave's 16 rows into ztile ----
            const int base = tile * 64 + wave * 16;
            for (int i = 0; i < 16; ++i) {
                const int row = base + i;
                if (row < NN) {
                    const int beg = rfl(rowbeg[row]);
                    const int deg = rfl(counts[row]);
                    const int end = beg + deg;
                    float a[8];
                    #pragma unroll
                    for (int q = 0; q < 8; ++q) a[q] = 0.f;
                    a[0] = b2f(hin[row * 64 + lane]);   // self

                    if (deg <= 16) {
                        const int safeb = (beg < EE) ? beg : 0;
                        int c[16];
                        #pragma unroll
                        for (int t = 0; t < 16; ++t) {
                            const int jj = (t < deg) ? (beg + t) : safeb;
                            c[t] = rfl(col[jj]);
                        }
                        float hv[16];
                        #pragma unroll
                        for (int t = 0; t < 16; ++t) hv[t] = b2f(hin[c[t] * 64 + lane]);
                        #pragma unroll
                        for (int t = 0; t < 16; ++t) a[t & 7] += (t < deg) ? hv[t] : 0.f;
                    } else {
                        int j = beg;
                        for (; j + 16 <= end; j += 16) {
                            int c[16];
                            #pragma unroll
                            for (int t = 0; t < 16; ++t) c[t] = rfl(col[j + t]);
                            float hv[16];
                            #pragma unroll
                            for (int t = 0; t < 16; ++t) hv[t] = b2f(hin[c[t] * 64 + lane]);
                            #pragma unroll
                            for (int t = 0; t < 16; ++t) a[t & 7] += hv[t];
                        }
                        if (j < end) {
                            int c[16];
                            #pragma unroll
                            for (int t = 0; t < 16; ++t) {
                                const int jj = (j + t < end) ? (j + t) : beg;
                                c[t] = rfl(col[jj]);
                            }
                            float hv[16];
                            #pragma unroll
                            for (int t = 0; t < 16; ++t) hv[t] = b2f(hin[c[t] * 64 + lane]);
                            #pragma unroll
                            for (int t = 0; t < 16; ++t) a[t & 7] += (j + t < end) ? hv[t] : 0.f;
                        }
                    }
                    const float sum = ((a[0] + a[1]) + (a[2] + a[3])) + ((a[4] + a[5]) + (a[6] + a[7]));
                    ztile[wave * 16 + i][lane] = f2b(fmaf(sum, scl, (float)(deg + 1) * sft));
                } else {
                    ztile[wave * 16 + i][lane] = 0;
                }
            }
            __syncthreads();

            // ---- MFMA MLP ----
            const bool valid = base < NN;
            const int rloc = wave * 16 + l15;
            const short8 a0 = *(const short8*)(&ztile[rloc][quad * 8]);
            const short8 a1 = *(const short8*)(&ztile[rloc][32 + quad * 8]);

            f32x4 acc[4];
            #pragma unroll
            for (int nt = 0; nt < 4; ++nt) {
                f32x4 c = {0.f, 0.f, 0.f, 0.f};
                c = __builtin_amdgcn_mfma_f32_16x16x32_bf16(
                        a0, *(const short8*)(&wlds[(nt * 64 + lane) * 8]), c, 0, 0, 0);
                c = __builtin_amdgcn_mfma_f32_16x16x32_bf16(
                        a1, *(const short8*)(&wlds[((4 + nt) * 64 + lane) * 8]), c, 0, 0, 0);
                acc[nt] = c;
            }
            #pragma unroll
            for (int nt = 0; nt < 4; ++nt)
                #pragma unroll
                for (int r = 0; r < 4; ++r)
                    ldsT[wave][quad * 4 + r][nt * 16 + l15] =
                        f2b(fmaxf(acc[nt][r] + biasA[nt], 0.f));

            const short8 y0 = *(const short8*)(&ldsT[wave][l15][quad * 8]);
            const short8 y1 = *(const short8*)(&ldsT[wave][l15][32 + quad * 8]);

            #pragma unroll
            for (int nt = 0; nt < 4; ++nt) {
                f32x4 c = {0.f, 0.f, 0.f, 0.f};
                c = __builtin_amdgcn_mfma_f32_16x16x32_bf16(
                        y0, *(const short8*)(&wlds[4096 + (nt * 64 + lane) * 8]), c, 0, 0, 0);
                c = __builtin_amdgcn_mfma_f32_16x16x32_bf16(
                        y1, *(const short8*)(&wlds[4096 + ((4 + nt) * 64 + lane) * 8]), c, 0, 0, 0);
                acc[nt] = c;
            }
            #pragma unroll
            for (int nt = 0; nt < 4; ++nt)
                #pragma unroll
                for (int r = 0; r < 4; ++r)
                    ldsT[wave][quad * 4 + r][nt * 16 + l15] =
                        f2b(fmaxf(acc[nt][r] + biasB[nt], 0.f));

            // BN partials (fabric atomics into statsL)
            {
                float s = 0.f, sq = 0.f;
                if (valid) {
                    #pragma unroll 4
                    for (int r = 0; r < 16; ++r) {
                        const float v = b2f(ldsT[wave][r][lane]);
                        s += v;
                        sq += v * v;
                    }
                }
                red[wave * 128 + lane] = s;
                red[wave * 128 + 64 + lane] = sq;
            }
            __syncthreads();
            if (threadIdx.x < 128) {
                const float tot = red[threadIdx.x] + red[128 + threadIdx.x] +
                                  red[256 + threadIdx.x] + red[384 + threadIdx.x];
                atomicAdd(&statsL[(tile & 7) * 128 + threadIdx.x], tot);
            }

            if (l < 2) {
                // write tout (normal stores; wb'd at this layer's LBAR)
                #pragma unroll
                for (int m = 0; m < 4; ++m) {
                    const int g = m * 256 + threadIdx.x;
                    const int r = g >> 4;
                    const int f4 = (g & 15) * 4;
                    const int grow = tile * 64 + r;
                    if (grow < NN)
                        *(ushort4*)(tout + grow * 64 + f4) =
                            *(const ushort4*)(&ldsT[r >> 4][r & 15][f4]);
                }
            } else {
                // folded pool: raw (pre-BN) per-graph sums via fabric atomics
                if (valid) {
                    int gprev = rfl(p.batch[base]);
                    float acc2 = 0.f;
                    for (int i = 0; i < 16; ++i) {
                        const int row = base + i;
                        const int g = rfl(p.batch[row]);
                        const float v = b2f(ldsT[wave][i][lane]);
                        if (g != gprev) {
                            atomicAdd(&xpool[gprev * 64 + lane], acc2);
                            acc2 = 0.f;
                            gprev = g;
                        }
                        acc2 += v;
                    }
                    atomicAdd(&xpool[gprev * 64 + lane], acc2);
                }
            }
        }
        // k = 4+l ; wb needed only when tout was normally written (l<2)
        if (l == 0)      LBAR(4, 1);
        else if (l == 1) LBAR(5, 1);
        else             LBAR(6, 0);
    }

    // ================= head: 2 graphs per block, blocks 0..255 =================
    if (blockIdx.x < GG / 2) {
        float* hxp  = (float*)smraw;         // [2][64]
        float* hmid = (float*)smraw + 128;   // [2][128]
        const int half = threadIdx.x >> 7;
        const int tt = threadIdx.x & 127;
        const int g = blockIdx.x * 2 + half;
        if (tt < 64) {
            // finalize BN-3 for feature tt (stats/xpool fabric-written, first normal read)
            const float* st3 = stats + 2048;
            float s = 0.f, sq = 0.f;
            #pragma unroll
            for (int k = 0; k < 8; ++k) {
                s += st3[k * 128 + tt];
                sq += st3[k * 128 + 64 + tt];
            }
            const float mean = s * (1.0f / NN);
            const float var = sq * (1.0f / NN) - mean * mean;
            const float scl = p.g3[tt] * rsqrtf(var + 1e-5f);
            const float sft = p.be3[tt] - mean * scl;
            const int cnt = lowb(p.batch, g + 1) - lowb(p.batch, g);
            hxp[half * 64 + tt] = fmaf(xpool[g * 64 + tt], scl, (float)cnt * sft);
        }
        __syncthreads();
        float acc = p.blin0[tt];
        #pragma unroll 8
        for (int k = 0; k < 64; ++k) acc = fmaf(hxp[half * 64 + k], p.wlin0[k * 128 + tt], acc);
        hmid[half * 128 + tt] = acc;
        __syncthreads();
        if (tt < 64) {
            float a2 = p.bfc1[tt];
            #pragma unroll 8
            for (int k = 0; k < 128; ++k) a2 = fmaf(hmid[half * 128 + k], p.wfc1[k * 64 + tt], a2);
            p.out[g * 64 + tt] = fmaxf(a2, 0.f);
        }
    }
#undef LBAR
}

extern "C" void kernel_launch(void* const* d_in, const int* in_sizes, int n_in,
                              void* d_out, int out_size, void* d_ws, size_t ws_size,
                              hipStream_t stream) {
    Params p;
    p.x     = (const float*)d_in[0];
    p.ei    = (const int*)d_in[1];
    p.batch = (const int*)d_in[2];
    p.w1a = (const float*)d_in[3];  p.b1a = (const float*)d_in[4];
    p.w1b = (const float*)d_in[5];  p.b1b = (const float*)d_in[6];
    p.g1  = (const float*)d_in[7];  p.be1 = (const float*)d_in[8];
    p.w2a = (const float*)d_in[9];  p.b2a = (const float*)d_in[10];
    p.w2b = (const float*)d_in[11]; p.b2b = (const float*)d_in[12];
    p.g2  = (const float*)d_in[13]; p.be2 = (const float*)d_in[14];
    p.w3a = (const float*)d_in[15]; p.b3a = (const float*)d_in[16];
    p.w3b = (const float*)d_in[17]; p.b3b = (const float*)d_in[18];
    p.g3  = (const float*)d_in[19]; p.be3 = (const float*)d_in[20];
    p.wlin0 = (const float*)d_in[21]; p.blin0 = (const float*)d_in[22];
    p.wfc1  = (const float*)d_in[23]; p.bfc1  = (const float*)d_in[24];
    p.out = (float*)d_out;
    p.ws  = d_ws;

    int* ctrl = (int*)d_ws + 150000;
    init_kernel<<<1, 64, 0, stream>>>(ctrl);
    mega_kernel<<<NBLK, NTHR, 0, stream>>>(p);
}

// Round 9
// 361.616 us; speedup vs baseline: 5.3025x; 1.4828x over previous
//
#include <hip/hip_runtime.h>

#define NN 50000
#define EE 800000
#define GG 512
#define TILES 782          // ceil(NN/64)
#define CSRB 256           // blocks in the persistent CSR kernel

typedef __attribute__((ext_vector_type(8))) short short8;
typedef __attribute__((ext_vector_type(4))) float f32x4;

__device__ __forceinline__ float b2f(unsigned short u) {
    union { unsigned int i; float f; } c;
    c.i = ((unsigned int)u) << 16;
    return c.f;
}
__device__ __forceinline__ unsigned short f2b(float f) {
    union { float f; unsigned int i; } c;
    c.f = f;
    const unsigned int r = c.i + 0x7FFFu + ((c.i >> 16) & 1u);  // rne
    return (unsigned short)(r >> 16);
}
__device__ __forceinline__ int rfl(int v) { return __builtin_amdgcn_readfirstlane(v); }

__device__ __forceinline__ int lowb(const int* b, int v) {
    int lo = 0, hi = NN;
    while (lo < hi) { const int m = (lo + hi) >> 1; if (b[m] < v) lo = m + 1; else hi = m; }
    return lo;
}

// ===========================================================================
// prep: x fp32->bf16, zero counts/ctrl/stats/xpool, weight swizzle (last 6
// blocks). Normal stores are fine: kernel-end flush makes them visible to
// the next kernel's fabric atomics (rounds 6-8 evidence).
// ===========================================================================
__global__ __launch_bounds__(256) void prep_kernel(const float* __restrict__ x,
                                                   unsigned short* __restrict__ xbf,
                                                   int* __restrict__ counts,
                                                   int* __restrict__ ctrl,
                                                   float* __restrict__ zblock,
                                                   const float* __restrict__ w0,
                                                   const float* __restrict__ w1,
                                                   const float* __restrict__ w2,
                                                   const float* __restrict__ w3,
                                                   const float* __restrict__ w4,
                                                   const float* __restrict__ w5,
                                                   unsigned short* __restrict__ wfrag) {
    if (blockIdx.x >= 3210) {   // weight swizzle: fp32 [k][n] -> B-frag order
        const float* ws[6] = {w0, w1, w2, w3, w4, w5};
        const int wi = blockIdx.x - 3210;
        const float* w = ws[wi];
        unsigned short* o = wfrag + wi * 4096;
        #pragma unroll
        for (int it = 0; it < 2; ++it) {
            const int idx = it * 256 + threadIdx.x;
            const int fid = idx >> 6, lane = idx & 63;
            const int kt = fid >> 2, nt = fid & 3;
            const int kbase = kt * 32 + (lane >> 4) * 8;
            const int n = nt * 16 + (lane & 15);
            #pragma unroll
            for (int j = 0; j < 8; ++j)
                o[idx * 8 + j] = f2b(w[(kbase + j) * 64 + n]);
        }
        return;
    }
    const int tid = blockIdx.x * 256 + threadIdx.x;
    if (tid < 800000) {
        const float4 v = ((const float4*)x)[tid];
        ushort4 o;
        o.x = f2b(v.x); o.y = f2b(v.y); o.z = f2b(v.z); o.w = f2b(v.w);
        ((ushort4*)xbf)[tid] = o;
    } else if (tid < 812500) {
        ((int4*)counts)[tid - 800000] = make_int4(0, 0, 0, 0);
    } else if (tid < 812756) {
        ((int4*)ctrl)[tid - 812500] = make_int4(0, 0, 0, 0);
    } else if (tid < 821716) {   // stats (3072) + xpool (32768) floats
        ((float4*)zblock)[tid - 812756] = make_float4(0.f, 0.f, 0.f, 0.f);
    }
}

// ===========================================================================
// Persistent CSR build: hist -> alloc (order-free wave-scan) -> fill, one
// kernel, 256 blocks, two FLAT fence-free barriers (all cross-phase state is
// fabric-atomic; bulk outputs read only after kernel end).
// ===========================================================================
__global__ __launch_bounds__(256, 4) void csr_kernel(const int* __restrict__ ei,
                                                     int* __restrict__ counts,
                                                     int* __restrict__ rowbeg,
                                                     int* __restrict__ cursor,
                                                     int* __restrict__ ctrl,
                                                     int* __restrict__ col) {
    const int gtid = blockIdx.x * 256 + threadIdx.x;
    const int lane = threadIdx.x & 63;

#define CBAR(slot) do {                                                        \
        __syncthreads();                                                       \
        if (threadIdx.x == 0) {                                                \
            __hip_atomic_fetch_add(&ctrl[slot], 1, __ATOMIC_RELAXED,           \
                                   __HIP_MEMORY_SCOPE_AGENT);                  \
            int sp = 0;                                                        \
            while (__hip_atomic_load(&ctrl[slot], __ATOMIC_RELAXED,            \
                                     __HIP_MEMORY_SCOPE_AGENT) < CSRB) {       \
                __builtin_amdgcn_s_sleep(2);                                   \
                if (++sp > (1 << 20)) break;                                   \
            }                                                                  \
        }                                                                      \
        __syncthreads();                                                       \
    } while (0)

    // ---- A: histogram (fabric RMW) ----
    for (int e = gtid; e < EE; e += CSRB * 256) atomicAdd(&counts[ei[EE + e]], 1);
    CBAR(128);

    // ---- B: alloc (order-free rowbeg; wave scan + one atomic per wave) ----
    {
        const int gw = gtid >> 6;
        if (gw < TILES) {
            const int r = gw * 64 + lane;
            const int cnt = (r < NN) ? counts[r] : 0;   // normal read post-final (miss->home)
            int incl = cnt;
            #pragma unroll
            for (int off = 1; off < 64; off <<= 1) {
                const int tv = __shfl_up(incl, off);
                if (lane >= off) incl += tv;
            }
            const int tot = __shfl(incl, 63);
            int base = 0;
            if (lane == 63)
                base = __hip_atomic_fetch_add(&ctrl[64], tot, __ATOMIC_RELAXED,
                                              __HIP_MEMORY_SCOPE_AGENT);
            base = __shfl(base, 63);
            if (r < NN) {
                const int b0 = base + incl - cnt;
                rowbeg[r] = b0;                           // read after kernel end
                __hip_atomic_store(&cursor[r], b0, __ATOMIC_RELAXED,
                                   __HIP_MEMORY_SCOPE_AGENT);   // fabric (C RMWs it)
            }
        }
    }
    CBAR(160);

    // ---- C: fill (8 classes x 32 chunk-blocks) ----
    {
        const int cls = blockIdx.x & 7;
        for (int e = (blockIdx.x >> 3) * 256 + threadIdx.x; e < EE; e += 32 * 256) {
            const int dst = ei[EE + e];
            if (dst / 6250 == cls) {
                const int pos = atomicAdd(&cursor[dst], 1);
                col[pos] = ei[e];
            }
        }
    }
#undef CBAR
}

// ===========================================================================
// Gather (round-0 proven): one wave per row, deg-adaptive batches, previous
// layer's BN finalize folded. z = scl.*(h_self + sum_nbr h) + (deg+1).*sft
// ===========================================================================
__global__ __launch_bounds__(256, 4) void gather_kernel(const unsigned short* __restrict__ hin,
                                                        const int* __restrict__ rowbeg,
                                                        const int* __restrict__ counts,
                                                        const int* __restrict__ col,
                                                        const float* __restrict__ stats,
                                                        const float* __restrict__ ga,
                                                        const float* __restrict__ be,
                                                        const int apply,
                                                        unsigned short* __restrict__ z) {
    const int wv = (blockIdx.x * 256 + threadIdx.x) >> 6;
    const int lane = threadIdx.x & 63;
    const int row = rfl(wv);
    if (row >= NN) return;

    float scl = 1.0f, sft = 0.0f;
    if (apply) {
        float s = 0.f, sq = 0.f;
        #pragma unroll
        for (int k = 0; k < 8; ++k) {
            s += stats[k * 128 + lane];
            sq += stats[k * 128 + 64 + lane];
        }
        const float mean = s * (1.0f / NN);
        const float var = sq * (1.0f / NN) - mean * mean;
        scl = ga[lane] * rsqrtf(var + 1e-5f);
        sft = be[lane] - mean * scl;
    }

    const int beg = rfl(rowbeg[row]);
    const int deg = rfl(counts[row]);
    const int end = beg + deg;
    float a[8];
    #pragma unroll
    for (int i = 0; i < 8; ++i) a[i] = 0.f;
    a[0] = b2f(hin[row * 64 + lane]);   // self term

    if (deg <= 16) {
        const int safeb = (beg < EE) ? beg : 0;
        int c[16];
        #pragma unroll
        for (int i = 0; i < 16; ++i) {
            const int jj = (i < deg) ? (beg + i) : safeb;
            c[i] = rfl(col[jj]);
        }
        float hv[16];
        #pragma unroll
        for (int i = 0; i < 16; ++i) hv[i] = b2f(hin[c[i] * 64 + lane]);
        #pragma unroll
        for (int i = 0; i < 16; ++i) a[i & 7] += (i < deg) ? hv[i] : 0.f;
    } else if (deg <= 24) {
        int c[24];
        #pragma unroll
        for (int i = 0; i < 24; ++i) {
            const int jj = (i < deg) ? (beg + i) : beg;
            c[i] = rfl(col[jj]);
        }
        float hv[24];
        #pragma unroll
        for (int i = 0; i < 24; ++i) hv[i] = b2f(hin[c[i] * 64 + lane]);
        #pragma unroll
        for (int i = 0; i < 24; ++i) a[i & 7] += (i < deg) ? hv[i] : 0.f;
    } else if (deg <= 32) {
        int c[32];
        #pragma unroll
        for (int i = 0; i < 32; ++i) {
            const int jj = (i < deg) ? (beg + i) : beg;
            c[i] = rfl(col[jj]);
        }
        float hv[32];
        #pragma unroll
        for (int i = 0; i < 32; ++i) hv[i] = b2f(hin[c[i] * 64 + lane]);
        #pragma unroll
        for (int i = 0; i < 32; ++i) a[i & 7] += (i < deg) ? hv[i] : 0.f;
    } else {
        int j = beg;
        for (; j + 16 <= end; j += 16) {
            int c[16];
            #pragma unroll
            for (int i = 0; i < 16; ++i) c[i] = rfl(col[j + i]);
            float hv[16];
            #pragma unroll
            for (int i = 0; i < 16; ++i) hv[i] = b2f(hin[c[i] * 64 + lane]);
            #pragma unroll
            for (int i = 0; i < 16; ++i) a[i & 7] += hv[i];
        }
        if (j < end) {
            int c[16];
            #pragma unroll
            for (int i = 0; i < 16; ++i) {
                const int jj = (j + i < end) ? (j + i) : beg;
                c[i] = rfl(col[jj]);
            }
            float hv[16];
            #pragma unroll
            for (int i = 0; i < 16; ++i) hv[i] = b2f(hin[c[i] * 64 + lane]);
            #pragma unroll
            for (int i = 0; i < 16; ++i) a[i & 7] += (j + i < end) ? hv[i] : 0.f;
        }
    }
    const float sum = ((a[0] + a[1]) + (a[2] + a[3])) + ((a[4] + a[5]) + (a[6] + a[7]));
    z[row * 64 + lane] = f2b(fmaf(sum, scl, (float)(deg + 1) * sft));
}

// ===========================================================================
// MFMA MLP (round-0 proven, reg-weights, (256,2)). dopool: instead of
// writing tout, accumulate RAW per-graph sums into xpool (BN3 finalize is
// affine -> applied in head: sum(bn(t)) = scl*sum(t) + cnt*sft).
// ===========================================================================
__global__ __launch_bounds__(256, 2) void mlp_kernel(const unsigned short* __restrict__ z,
                                                     const unsigned short* __restrict__ wfa,
                                                     const float* __restrict__ ba,
                                                     const unsigned short* __restrict__ wfb,
                                                     const float* __restrict__ bb,
                                                     unsigned short* __restrict__ tout,
                                                     float* __restrict__ stats,
                                                     const int* __restrict__ batch,
                                                     float* __restrict__ xpool,
                                                     const int dopool) {
    __shared__ unsigned short ldsT[4][16][72];
    __shared__ float red[512];

    const int wave = threadIdx.x >> 6;
    const int lane = threadIdx.x & 63;
    const int quad = lane >> 4;
    const int l15 = lane & 15;
    const int rowbase = blockIdx.x * 64 + wave * 16;
    const bool valid = rowbase < NN;

    short8 wA[8], wB[8];
    #pragma unroll
    for (int f = 0; f < 8; ++f) {
        wA[f] = *(const short8*)(wfa + (f * 64 + lane) * 8);
        wB[f] = *(const short8*)(wfb + (f * 64 + lane) * 8);
    }
    float biasA[4], biasB[4];
    #pragma unroll
    for (int nt = 0; nt < 4; ++nt) {
        biasA[nt] = ba[nt * 16 + l15];
        biasB[nt] = bb[nt * 16 + l15];
    }

    const int arow = valid ? (rowbase + l15) : 0;
    const short8 a0 = *(const short8*)(z + arow * 64 + quad * 8);
    const short8 a1 = *(const short8*)(z + arow * 64 + 32 + quad * 8);

    f32x4 acc[4];
    #pragma unroll
    for (int nt = 0; nt < 4; ++nt) {
        f32x4 c = {0.f, 0.f, 0.f, 0.f};
        c = __builtin_amdgcn_mfma_f32_16x16x32_bf16(a0, wA[nt], c, 0, 0, 0);
        c = __builtin_amdgcn_mfma_f32_16x16x32_bf16(a1, wA[4 + nt], c, 0, 0, 0);
        acc[nt] = c;
    }
    #pragma unroll
    for (int nt = 0; nt < 4; ++nt)
        #pragma unroll
        for (int r = 0; r < 4; ++r)
            ldsT[wave][quad * 4 + r][nt * 16 + l15] =
                f2b(fmaxf(acc[nt][r] + biasA[nt], 0.f));

    const short8 y0 = *(const short8*)(&ldsT[wave][l15][quad * 8]);
    const short8 y1 = *(const short8*)(&ldsT[wave][l15][32 + quad * 8]);

    #pragma unroll
    for (int nt = 0; nt < 4; ++nt) {
        f32x4 c = {0.f, 0.f, 0.f, 0.f};
        c = __builtin_amdgcn_mfma_f32_16x16x32_bf16(y0, wB[nt], c, 0, 0, 0);
        c = __builtin_amdgcn_mfma_f32_16x16x32_bf16(y1, wB[4 + nt], c, 0, 0, 0);
        acc[nt] = c;
    }
    #pragma unroll
    for (int nt = 0; nt < 4; ++nt)
        #pragma unroll
        for (int r = 0; r < 4; ++r)
            ldsT[wave][quad * 4 + r][nt * 16 + l15] =
                f2b(fmaxf(acc[nt][r] + biasB[nt], 0.f));

    // BN partials (wave reads its own region; same-wave ordered)
    {
        float s = 0.f, sq = 0.f;
        if (valid) {
            #pragma unroll 4
            for (int r = 0; r < 16; ++r) {
                const float v = b2f(ldsT[wave][r][lane]);
                s += v;
                sq += v * v;
            }
        }
        red[wave * 128 + lane] = s;
        red[wave * 128 + 64 + lane] = sq;
    }
    __syncthreads();

    if (threadIdx.x < 128) {
        const float tot = red[threadIdx.x] + red[128 + threadIdx.x] +
                          red[256 + threadIdx.x] + red[384 + threadIdx.x];
        atomicAdd(&stats[(blockIdx.x & 7) * 128 + threadIdx.x], tot);
    }

    if (!dopool) {
        #pragma unroll
        for (int m = 0; m < 4; ++m) {
            const int g = m * 256 + threadIdx.x;
            const int r = g >> 4;
            const int f4 = (g & 15) * 4;
            const int grow = blockIdx.x * 64 + r;
            if (grow < NN)
                *(ushort4*)(tout + grow * 64 + f4) =
                    *(const ushort4*)(&ldsT[r >> 4][r & 15][f4]);
        }
    } else if (valid) {
        // folded pool: raw (pre-BN) per-graph sums (batch sorted)
        int gprev = rfl(batch[rowbase]);
        float acc2 = 0.f;
        for (int i = 0; i < 16; ++i) {
            const int row = rowbase + i;
            if (row >= NN) break;
            const int g = rfl(batch[row]);
            const float v = b2f(ldsT[wave][i][lane]);
            if (g != gprev) {
                atomicAdd(&xpool[gprev * 64 + lane], acc2);
                acc2 = 0.f;
                gprev = g;
            }
            acc2 += v;
        }
        atomicAdd(&xpool[gprev * 64 + lane], acc2);
    }
}

// ===========================================================================
// Head: BN3 finalize (raw xpool + cnt*sft via binary search) + 2-layer MLP.
// ===========================================================================
__global__ __launch_bounds__(128) void head_kernel(const float* __restrict__ xpool,
                                                   const int* __restrict__ batch,
                                                   const float* __restrict__ stats,
                                                   const float* __restrict__ g3,
                                                   const float* __restrict__ be3,
                                                   const float* __restrict__ w0,
                                                   const float* __restrict__ b0,
                                                   const float* __restrict__ w1,
                                                   const float* __restrict__ b1,
                                                   float* __restrict__ out) {
    __shared__ float xp[64];
    __shared__ float midl[128];
    const int g = blockIdx.x;
    const int t = threadIdx.x;
    if (t < 64) {
        float s = 0.f, sq = 0.f;
        #pragma unroll
        for (int k = 0; k < 8; ++k) {
            s += stats[k * 128 + t];
            sq += stats[k * 128 + 64 + t];
        }
        const float mean = s * (1.0f / NN);
        const float var = sq * (1.0f / NN) - mean * mean;
        const float scl = g3[t] * rsqrtf(var + 1e-5f);
        const float sft = be3[t] - mean * scl;
        const int cnt = lowb(batch, g + 1) - lowb(batch, g);
        xp[t] = fmaf(xpool[g * 64 + t], scl, (float)cnt * sft);
    }
    __syncthreads();
    float acc = b0[t];
    #pragma unroll 8
    for (int k = 0; k < 64; ++k) acc = fmaf(xp[k], w0[k * 128 + t], acc);
    midl[t] = acc;
    __syncthreads();
    if (t < 64) {
        float a2 = b1[t];
        #pragma unroll 8
        for (int k = 0; k < 128; ++k) a2 = fmaf(midl[k], w1[k * 64 + t], a2);
        out[g * 64 + t] = fmaxf(a2, 0.f);
    }
}

extern "C" void kernel_launch(void* const* d_in, const int* in_sizes, int n_in,
                              void* d_out, int out_size, void* d_ws, size_t ws_size,
                              hipStream_t stream) {
    const float* x = (const float*)d_in[0];
    const int* ei = (const int*)d_in[1];
    const int* batch = (const int*)d_in[2];

    // ---- workspace layout ----
    int* ibase   = (int*)d_ws;
    int* counts  = ibase;            // 50000
    int* rowbeg  = ibase + 50000;    // 50000
    int* cursor  = ibase + 100000;   // 50000
    int* ctrl    = ibase + 150000;   // 1024 (zeroed by prep)
    int* col     = ibase + 151040;   // 800000 -> end 951040
    float* fbase = (float*)d_ws + 951040;
    float* stats = fbase;            // 3 x 1024
    float* xpool = stats + 3072;     // 32768 (raw pre-BN sums)
    unsigned short* zbf   = (unsigned short*)(fbase + 35840);  // NN*64
    unsigned short* xbf   = zbf + 3200000;
    unsigned short* t0bf  = xbf + 3200000;
    unsigned short* t1bf  = t0bf + 3200000;
    unsigned short* wfrag = t1bf + 3200000;      // 6 x 4096 bf16

    prep_kernel<<<3216, 256, 0, stream>>>(x, xbf, counts, ctrl, stats,
                                          (const float*)d_in[3], (const float*)d_in[5],
                                          (const float*)d_in[9], (const float*)d_in[11],
                                          (const float*)d_in[15], (const float*)d_in[17],
                                          wfrag);
    csr_kernel<<<CSRB, 256, 0, stream>>>(ei, counts, rowbeg, cursor, ctrl, col);

    const unsigned short* hcur = xbf;
    unsigned short* touts[3] = {t0bf, t1bf, t0bf};
    for (int l = 0; l < 3; ++l) {
        const float* ba = (const float*)d_in[3 + l * 6 + 1];
        const float* bb = (const float*)d_in[3 + l * 6 + 3];
        const float* gp = (const float*)d_in[3 + (l ? (l - 1) : 0) * 6 + 4];
        const float* bp = (const float*)d_in[3 + (l ? (l - 1) : 0) * 6 + 5];

        gather_kernel<<<12500, 256, 0, stream>>>(hcur, rowbeg, counts, col,
                                                 stats + (l ? (l - 1) : 0) * 1024,
                                                 gp, bp, l > 0, zbf);
        mlp_kernel<<<TILES, 256, 0, stream>>>(zbf,
                                              wfrag + (l * 2 + 0) * 4096, ba,
                                              wfrag + (l * 2 + 1) * 4096, bb,
                                              touts[l], stats + l * 1024,
                                              batch, xpool, (l == 2) ? 1 : 0);
        hcur = touts[l];
    }

    head_kernel<<<GG, 128, 0, stream>>>(
        xpool, batch, stats + 2048,
        (const float*)d_in[19], (const float*)d_in[20],
        (const float*)d_in[21], (const float*)d_in[22],
        (const float*)d_in[23], (const float*)d_in[24], (float*)d_out);
}